// Round 3
// baseline (156.588 us; speedup 1.0000x reference)
//
#include <hip/hip_runtime.h>

#define NTOK 8192
#define DDIM 1024
#define NEXP 16
#define NPAIR 136   // E*(E+1)/2 pairs with e<=f
#define NREP 64     // s_glob replicas (16 blocks/address, ~256 atomics/line)
#define XROW 1032   // LDS x-tile row stride in floats (pad 8: 2-way alias only)
#define NBLK 1024   // fused grid size (ticket target)

// ws layout (floats): gwT4 [256*16 float4] = 16384 f | s_glob [NREP*1024] | ticket (1 int)
// ws arena is 256 MiB (poison fill WRITE_SIZE) — plenty of headroom.
#define WS_GWT 0
#define WS_SG  16384
#define WS_CNT (WS_SG + NREP * DDIM)   // float-index 81920, used as int slot

// ---------------------------------------------------------------------------
// Prep: transpose gate_w [16][1024] -> gwT4[d4][e] (float4 over d, expert-
// contiguous) so routing reads are fully coalesced. Zeroes s_glob + ticket.
// ---------------------------------------------------------------------------
__global__ __launch_bounds__(256) void moe_prep(
    const float* __restrict__ gate_w,
    float* __restrict__ ws)
{
    const int gid = blockIdx.x * 256 + threadIdx.x;   // 0..4095
    const int e = gid & 15;
    const int d4 = gid >> 4;                          // 0..255
    const float4* gw4 = (const float4*)gate_w;
    float4* gwT4 = (float4*)(ws + WS_GWT);
    gwT4[d4 * 16 + e] = gw4[e * 256 + d4];
    float* s_glob = ws + WS_SG;
    #pragma unroll
    for (int r = 0; r < NREP / 4; ++r)                // 16 stores: 64K floats
        s_glob[gid + r * 4096] = 0.f;
    if (gid == 0) ((int*)ws)[WS_CNT] = 0;             // ticket counter
}

// ---------------------------------------------------------------------------
// Fused: 1024 blocks x 256 thr, 8 tokens/block.
// A: x-tile -> LDS (coalesced, once); thread t owns d-cols 4t..4t+3 ->
//    x^2 column partials with no reduction needed.
// B: routing from LDS x (broadcast) + gwT (coalesced).
// C: top2 shfl scan (stable, matches lax.top_k).
// D: combine; x from LDS, re rows L1-hot, coalesced float4 out.
// A'(LATE): x^2 atomics issued AFTER D (round-0 position) — phases B-D run on
//    a clean memory system; the contended-storm tail is only exposed at the
//    pre-ticket barrier, and NREP=64 keeps that tail small.
// E: ticket; last block acquires (single __threadfence) and computes the
//    diversity loss from s_glob + L2-hot re.
// ---------------------------------------------------------------------------
__global__ __launch_bounds__(256, 4) void moe_fused(
    const float* __restrict__ x,
    const float* __restrict__ gate_b,
    const float* __restrict__ sh,
    const float* __restrict__ re,
    float* __restrict__ out,
    float* __restrict__ ws)
{
    __shared__ __align__(16) float xt[8][XROW];
    __shared__ float nr[NEXP];
    __shared__ float lsum;
    __shared__ int   is_last;

    const int t = threadIdx.x;
    const int b = blockIdx.x;
    const float4* gwT4 = (const float4*)(ws + WS_GWT);
    float* s_glob = ws + WS_SG;

    // ---- A: stage 8 token rows, accumulate x^2 for owned d-columns ----
    float4 ss = make_float4(0.f, 0.f, 0.f, 0.f);
    {
        const float4* x4 = (const float4*)x + (size_t)b * 2048;
        #pragma unroll
        for (int i = 0; i < 8; ++i) {
            float4 v = x4[i * 256 + t];
            *(float4*)&xt[i][4 * t] = v;
            ss.x = fmaf(v.x, v.x, ss.x);
            ss.y = fmaf(v.y, v.y, ss.y);
            ss.z = fmaf(v.z, v.z, ss.z);
            ss.w = fmaf(v.w, v.w, ss.w);
        }
    }
    __syncthreads();

    const int lane = t & 63;
    const int wave = t >> 6;
    const int e = lane & 15;
    const int h = (lane >> 4) & 1;
    const int g = lane >> 5;

    // ---- B: routing ----
    const int tokL = wave * 2 + g;
    const float* xrow = &xt[tokL][h * 512];
    const float4* gt = gwT4 + h * 128 * 16;
    float4 a4 = make_float4(0.f, 0.f, 0.f, 0.f);
    #pragma unroll 8
    for (int i = 0; i < 128; ++i) {
        float4 xv = *(const float4*)(xrow + 4 * i);  // 4 distinct addrs, bcast
        float4 gv = gt[i * 16 + e];                  // 256B contiguous / 16 lanes
        a4.x = fmaf(xv.x, gv.x, a4.x);
        a4.y = fmaf(xv.y, gv.y, a4.y);
        a4.z = fmaf(xv.z, gv.z, a4.z);
        a4.w = fmaf(xv.w, gv.w, a4.w);
    }
    float acc = (a4.x + a4.y) + (a4.z + a4.w);
    acc += __shfl_xor(acc, 16, 64);                  // merge d-halves
    acc += gate_b[e];

    // ---- C: stable top2 scan in this token's 16 expert lanes ----
    float v0 = -3.0e38f, v1 = -3.0e38f;
    int i0 = 0, i1 = 0;
    const int base = lane & 32;
    #pragma unroll
    for (int j = 0; j < NEXP; ++j) {
        float lv = __shfl(acc, base + j, 64);
        if (lv > v0)      { v1 = v0; i1 = i0; v0 = lv; i0 = j; }
        else if (lv > v1) { v1 = lv; i1 = j; }
    }
    float ex = __expf(v1 - v0);                      // softmax denom cancels
    float w0 = 1.f / (1.f + ex);
    float w1 = ex * w0;

    // hoisted shared-expert column sum for combine slots
    float4 shs[4];
    {
        const float4* s0 = (const float4*)sh;
        const float4* s1 = (const float4*)(sh + DDIM);
        #pragma unroll
        for (int j = 0; j < 4; ++j) {
            float4 p = s0[lane + 64 * j];
            float4 q = s1[lane + 64 * j];
            shs[j] = make_float4(p.x + q.x, p.y + q.y, p.z + q.z, p.w + q.w);
        }
    }

    // ---- D: combine (x from LDS, coalesced out) ----
    #pragma unroll
    for (int tk = 0; tk < 2; ++tk) {
        const int src = tk << 5;
        float a0 = __shfl(w0, src, 64);
        float a1 = __shfl(w1, src, 64);
        int   e0 = __shfl(i0, src, 64);
        int   e1 = __shfl(i1, src, 64);
        const int tokL2 = wave * 2 + tk;
        const float4* xr = (const float4*)&xt[tokL2][0];
        const float4* r0 = (const float4*)(re + (size_t)e0 * DDIM);
        const float4* r1 = (const float4*)(re + (size_t)e1 * DDIM);
        float4* o = (float4*)(out + ((size_t)b * 8 + tokL2) * DDIM);
        #pragma unroll
        for (int j = 0; j < 4; ++j) {
            float4 xv = xr[lane + 64 * j];
            float4 b0 = r0[lane + 64 * j];
            float4 b1 = r1[lane + 64 * j];
            float4 r;
            r.x = xv.x * (shs[j].x + a0 * b0.x + a1 * b1.x);
            r.y = xv.y * (shs[j].y + a0 * b0.y + a1 * b1.y);
            r.z = xv.z * (shs[j].z + a0 * b0.z + a1 * b1.z);
            r.w = xv.w * (shs[j].w + a0 * b0.w + a1 * b1.w);
            o[lane + 64 * j] = r;
        }
    }

    // ---- A' (late): x^2 partials — thread owns its 4 d-columns ----
    {
        float* rep = s_glob + (size_t)(b & (NREP - 1)) * DDIM;
        atomicAdd(&rep[4 * t + 0], ss.x);
        atomicAdd(&rep[4 * t + 1], ss.y);
        atomicAdd(&rep[4 * t + 2], ss.z);
        atomicAdd(&rep[4 * t + 3], ss.w);
    }

    // ---- E: ticket; last block computes diversity loss ----
    // Barrier implies vmcnt(0): this block's s_glob atomics are complete at
    // the coherence point before its ticket increment (refcheck-proven R2).
    __syncthreads();
    if (t == 0) {
        int tk = atomicAdd((int*)ws + WS_CNT, 1);
        is_last = (tk == NBLK - 1);
    }
    __syncthreads();
    if (!is_last) return;
    __threadfence();   // acquire (last block only): invalidate before reading s_glob

    float* smem = &xt[0][0];                     // xt is dead now; reuse as s_loc
    {
        const float4* sg4 = (const float4*)s_glob;
        float4 a = sg4[t];
        #pragma unroll 8
        for (int r = 1; r < NREP; ++r) {
            float4 v = sg4[r * 256 + t];
            a.x += v.x; a.y += v.y; a.z += v.z; a.w += v.w;
        }
        ((float4*)smem)[t] = a;                  // s_loc[4t..4t+3]
    }
    if (t == 0) lsum = 0.f;
    __syncthreads();

    float gacc = 0.f;
    int pe = 0, pf = 0;
    if (t < NPAIR) {
        int rem = t;
        while (rem >= NEXP - pe) { rem -= NEXP - pe; ++pe; }
        pf = pe + rem;
        const float4* ra = (const float4*)(re + (size_t)pe * DDIM);   // L2-hot
        const float4* rb = (const float4*)(re + (size_t)pf * DDIM);
        const float4* sl = (const float4*)smem;                       // bcast reads
        #pragma unroll 4
        for (int i = 0; i < 256; ++i) {
            float4 s = sl[i];
            float4 u = ra[i];
            float4 v = rb[i];
            gacc = fmaf(s.x * u.x, v.x, gacc);
            gacc = fmaf(s.y * u.y, v.y, gacc);
            gacc = fmaf(s.z * u.z, v.z, gacc);
            gacc = fmaf(s.w * u.w, v.w, gacc);
        }
        if (pe == pf) nr[pe] = fmaxf(sqrtf(gacc), 1e-8f);
    }
    __syncthreads();
    if (t < NPAIR && pe != pf) {
        float sim = gacc / (nr[pe] * nr[pf]);
        sim = fminf(1.f, fmaxf(-1.f, sim));
        atomicAdd(&lsum, 2.f * sim);             // LDS atomic, 120 adds
    }
    __syncthreads();
    if (t == 0)
        out[(size_t)NTOK * DDIM] = lsum / (float)(NEXP * (NEXP - 1)) * 0.1f;
}

extern "C" void kernel_launch(void* const* d_in, const int* in_sizes, int n_in,
                              void* d_out, int out_size, void* d_ws, size_t ws_size,
                              hipStream_t stream) {
    const float* x  = (const float*)d_in[0];
    const float* gw = (const float*)d_in[1];
    const float* gb = (const float*)d_in[2];
    const float* sh = (const float*)d_in[3];
    const float* re = (const float*)d_in[4];
    float* out = (float*)d_out;
    float* ws = (float*)d_ws;   // needs (16384 + 64*1024)*4 + 4 ~= 328 KB (arena 256 MiB)

    moe_prep<<<16, 256, 0, stream>>>(gw, ws);
    moe_fused<<<NBLK, 256, 0, stream>>>(x, gb, sh, re, out, ws);
}

// Round 4
// 144.991 us; speedup vs baseline: 1.0800x; 1.0800x over previous
//
#include <hip/hip_runtime.h>

#define NTOK 8192
#define DDIM 1024
#define NEXP 16
#define NPAIR 136   // E*(E+1)/2 pairs with e<=f
#define XROW 1032   // LDS x-tile row stride in floats (pad 8: 2-way alias only)
#define NBLK 1024   // fused grid size
#define NGRP 64     // reduction groups (16 blocks each)

// ws layout (floats): gwT4 [16384] | S slots [1024*1024] | s_fin [1024] | counters (65 ints)
// ws arena is 256 MiB — plenty of headroom.
#define WS_GWT  0
#define WS_SLOT 16384
#define WS_FIN  (WS_SLOT + NBLK * DDIM)          // 1064960
#define WS_CNT  (WS_FIN + DDIM)                  // int index: [0..63] grp, [64] fin

// ---------------------------------------------------------------------------
// Prep: transpose gate_w [16][1024] -> gwT4[d4][e]; zero s_fin + counters.
// ---------------------------------------------------------------------------
__global__ __launch_bounds__(256) void moe_prep(
    const float* __restrict__ gate_w,
    float* __restrict__ ws)
{
    const int gid = blockIdx.x * 256 + threadIdx.x;   // 0..4095
    const int e = gid & 15;
    const int d4 = gid >> 4;                          // 0..255
    const float4* gw4 = (const float4*)gate_w;
    float4* gwT4 = (float4*)(ws + WS_GWT);
    gwT4[d4 * 16 + e] = gw4[e * 256 + d4];
    if (gid < DDIM) (ws + WS_FIN)[gid] = 0.f;
    if (gid < NGRP + 1) ((int*)ws)[WS_CNT + gid] = 0;
}

// ---------------------------------------------------------------------------
// Fused: 1024 blocks x 256 thr, 8 tokens/block.
// A: x-tile -> LDS; thread t owns d-cols 4t..4t+3 -> x^2 partials in regs.
// B: routing (LDS x broadcast + gwT coalesced). C: top2 shfl scan.
// D: combine, coalesced float4 out.
// E1: x^2 partial -> private slot via AGENT-scope plain stores (no RMW storm:
//     1M atomicAdds @ ~26 G/s measured == ~39 us; stores are BW-trivial).
//     vmcnt drained by barrier, then ONE group-ticket atomic per block.
// E2: 16th arriver per group reduces its 16 slots, atomicAdds 1024 floats
//     into s_fin (65K total RMWs ~ 2.5 us), fin ticket.
// E3: 64th group-finisher: acquire-inv, s_fin -> LDS, 136-pair Gram vs
//     L2-hot re, norms, clipped cosine mean (proven R2 tail).
// ---------------------------------------------------------------------------
__global__ __launch_bounds__(256, 4) void moe_fused(
    const float* __restrict__ x,
    const float* __restrict__ gate_b,
    const float* __restrict__ sh,
    const float* __restrict__ re,
    float* __restrict__ out,
    float* __restrict__ ws)
{
    __shared__ __align__(16) float xt[8][XROW];
    __shared__ float nr[NEXP];
    __shared__ float lsum;
    __shared__ int   role;

    const int t = threadIdx.x;
    const int b = blockIdx.x;
    const float4* gwT4 = (const float4*)(ws + WS_GWT);
    int* cnt = (int*)ws + WS_CNT;

    // ---- A: stage 8 token rows, accumulate x^2 for owned d-columns ----
    float4 ss = make_float4(0.f, 0.f, 0.f, 0.f);
    {
        const float4* x4 = (const float4*)x + (size_t)b * 2048;
        #pragma unroll
        for (int i = 0; i < 8; ++i) {
            float4 v = x4[i * 256 + t];
            *(float4*)&xt[i][4 * t] = v;
            ss.x = fmaf(v.x, v.x, ss.x);
            ss.y = fmaf(v.y, v.y, ss.y);
            ss.z = fmaf(v.z, v.z, ss.z);
            ss.w = fmaf(v.w, v.w, ss.w);
        }
    }
    __syncthreads();

    const int lane = t & 63;
    const int wave = t >> 6;
    const int e = lane & 15;
    const int h = (lane >> 4) & 1;
    const int g = lane >> 5;

    // ---- B: routing ----
    const int tokL = wave * 2 + g;
    const float* xrow = &xt[tokL][h * 512];
    const float4* gt = gwT4 + h * 128 * 16;
    float4 a4 = make_float4(0.f, 0.f, 0.f, 0.f);
    #pragma unroll 8
    for (int i = 0; i < 128; ++i) {
        float4 xv = *(const float4*)(xrow + 4 * i);  // 4 distinct addrs, bcast
        float4 gv = gt[i * 16 + e];                  // 256B contiguous / 16 lanes
        a4.x = fmaf(xv.x, gv.x, a4.x);
        a4.y = fmaf(xv.y, gv.y, a4.y);
        a4.z = fmaf(xv.z, gv.z, a4.z);
        a4.w = fmaf(xv.w, gv.w, a4.w);
    }
    float acc = (a4.x + a4.y) + (a4.z + a4.w);
    acc += __shfl_xor(acc, 16, 64);                  // merge d-halves
    acc += gate_b[e];

    // ---- C: stable top2 scan in this token's 16 expert lanes ----
    float v0 = -3.0e38f, v1 = -3.0e38f;
    int i0 = 0, i1 = 0;
    const int base = lane & 32;
    #pragma unroll
    for (int j = 0; j < NEXP; ++j) {
        float lv = __shfl(acc, base + j, 64);
        if (lv > v0)      { v1 = v0; i1 = i0; v0 = lv; i0 = j; }
        else if (lv > v1) { v1 = lv; i1 = j; }
    }
    float ex = __expf(v1 - v0);                      // softmax denom cancels
    float w0 = 1.f / (1.f + ex);
    float w1 = ex * w0;

    // hoisted shared-expert column sum for combine slots
    float4 shs[4];
    {
        const float4* s0 = (const float4*)sh;
        const float4* s1 = (const float4*)(sh + DDIM);
        #pragma unroll
        for (int j = 0; j < 4; ++j) {
            float4 p = s0[lane + 64 * j];
            float4 q = s1[lane + 64 * j];
            shs[j] = make_float4(p.x + q.x, p.y + q.y, p.z + q.z, p.w + q.w);
        }
    }

    // ---- D: combine (x from LDS, coalesced out) ----
    #pragma unroll
    for (int tk = 0; tk < 2; ++tk) {
        const int src = tk << 5;
        float a0 = __shfl(w0, src, 64);
        float a1 = __shfl(w1, src, 64);
        int   e0 = __shfl(i0, src, 64);
        int   e1 = __shfl(i1, src, 64);
        const int tokL2 = wave * 2 + tk;
        const float4* xr = (const float4*)&xt[tokL2][0];
        const float4* r0 = (const float4*)(re + (size_t)e0 * DDIM);
        const float4* r1 = (const float4*)(re + (size_t)e1 * DDIM);
        float4* o = (float4*)(out + ((size_t)b * 8 + tokL2) * DDIM);
        #pragma unroll
        for (int j = 0; j < 4; ++j) {
            float4 xv = xr[lane + 64 * j];
            float4 b0 = r0[lane + 64 * j];
            float4 b1 = r1[lane + 64 * j];
            float4 r;
            r.x = xv.x * (shs[j].x + a0 * b0.x + a1 * b1.x);
            r.y = xv.y * (shs[j].y + a0 * b0.y + a1 * b1.y);
            r.z = xv.z * (shs[j].z + a0 * b0.z + a1 * b1.z);
            r.w = xv.w * (shs[j].w + a0 * b0.w + a1 * b1.w);
            o[lane + 64 * j] = r;
        }
    }

    // ---- E1: slot store (agent-scope, device-visible plain stores) ----
    {
        float* slot = ws + WS_SLOT + (size_t)b * DDIM;
        __hip_atomic_store(&slot[4 * t + 0], ss.x, __ATOMIC_RELAXED, __HIP_MEMORY_SCOPE_AGENT);
        __hip_atomic_store(&slot[4 * t + 1], ss.y, __ATOMIC_RELAXED, __HIP_MEMORY_SCOPE_AGENT);
        __hip_atomic_store(&slot[4 * t + 2], ss.z, __ATOMIC_RELAXED, __HIP_MEMORY_SCOPE_AGENT);
        __hip_atomic_store(&slot[4 * t + 3], ss.w, __ATOMIC_RELAXED, __HIP_MEMORY_SCOPE_AGENT);
    }
    __syncthreads();   // vmcnt(0): slot stores globally visible before ticket
    if (t == 0) {
        int a = atomicAdd(&cnt[b & (NGRP - 1)], 1);
        role = (a == 15);
    }
    __syncthreads();
    if (!role) return;

    // ---- E2: group reducer (one block per group) ----
    __builtin_amdgcn_fence(__ATOMIC_ACQUIRE, "agent");   // inv only, no wb
    const int grp = b & (NGRP - 1);
    float4 racc;
    {
        const float4* sl4 = (const float4*)(ws + WS_SLOT) + (size_t)grp * 256 + t;
        racc = sl4[0];
        #pragma unroll
        for (int k = 1; k < 16; ++k) {
            float4 v = sl4[(size_t)k * 16384];   // slot grp+64k
            racc.x += v.x; racc.y += v.y; racc.z += v.z; racc.w += v.w;
        }
    }
    {
        float* s_fin = ws + WS_FIN;
        atomicAdd(&s_fin[4 * t + 0], racc.x);
        atomicAdd(&s_fin[4 * t + 1], racc.y);
        atomicAdd(&s_fin[4 * t + 2], racc.z);
        atomicAdd(&s_fin[4 * t + 3], racc.w);
    }
    __syncthreads();   // drain s_fin RMWs before fin ticket
    if (t == 0) {
        int f = atomicAdd(&cnt[NGRP], 1);
        role = (f == NGRP - 1);
    }
    __syncthreads();
    if (!role) return;

    // ---- E3: final block — diversity loss ----
    __builtin_amdgcn_fence(__ATOMIC_ACQUIRE, "agent");
    float* smem = &xt[0][0];                     // xt dead; reuse as s_loc[1024]
    {
        const float4* sf4 = (const float4*)(ws + WS_FIN);
        ((float4*)smem)[t] = sf4[t];
    }
    if (t == 0) lsum = 0.f;
    __syncthreads();

    float gacc = 0.f;
    int pe = 0, pf = 0;
    if (t < NPAIR) {
        int rem = t;
        while (rem >= NEXP - pe) { rem -= NEXP - pe; ++pe; }
        pf = pe + rem;
        const float4* ra = (const float4*)(re + (size_t)pe * DDIM);   // L2-hot
        const float4* rb = (const float4*)(re + (size_t)pf * DDIM);
        const float4* sl = (const float4*)smem;                       // bcast reads
        #pragma unroll 4
        for (int i = 0; i < 256; ++i) {
            float4 s = sl[i];
            float4 u = ra[i];
            float4 v = rb[i];
            gacc = fmaf(s.x * u.x, v.x, gacc);
            gacc = fmaf(s.y * u.y, v.y, gacc);
            gacc = fmaf(s.z * u.z, v.z, gacc);
            gacc = fmaf(s.w * u.w, v.w, gacc);
        }
        if (pe == pf) nr[pe] = fmaxf(sqrtf(gacc), 1e-8f);
    }
    __syncthreads();
    if (t < NPAIR && pe != pf) {
        float sim = gacc / (nr[pe] * nr[pf]);
        sim = fminf(1.f, fmaxf(-1.f, sim));
        atomicAdd(&lsum, 2.f * sim);             // LDS atomic, 120 adds
    }
    __syncthreads();
    if (t == 0)
        out[(size_t)NTOK * DDIM] = lsum / (float)(NEXP * (NEXP - 1)) * 0.1f;
}

extern "C" void kernel_launch(void* const* d_in, const int* in_sizes, int n_in,
                              void* d_out, int out_size, void* d_ws, size_t ws_size,
                              hipStream_t stream) {
    const float* x  = (const float*)d_in[0];
    const float* gw = (const float*)d_in[1];
    const float* gb = (const float*)d_in[2];
    const float* sh = (const float*)d_in[3];
    const float* re = (const float*)d_in[4];
    float* out = (float*)d_out;
    float* ws = (float*)d_ws;   // needs ~4.3 MB (arena 256 MiB)

    moe_prep<<<16, 256, 0, stream>>>(gw, ws);
    moe_fused<<<NBLK, 256, 0, stream>>>(x, gb, sh, re, out, ws);
}